// Round 1
// baseline (369.409 us; speedup 1.0000x reference)
//
#include <hip/hip_runtime.h>
#include <hip/hip_bf16.h>

// B=2, T=2048, C=1024, H=16, D=64, M=B*T=4096
// All GEMMs: exact integer math via bf16 MFMA (ints <= 2^24 exact in fp32 accum).

typedef __attribute__((ext_vector_type(8))) short bf16x8;
typedef __attribute__((ext_vector_type(4))) float f32x4;

__device__ __forceinline__ f32x4 mfma16(bf16x8 a, bf16x8 b, f32x4 c) {
    return __builtin_amdgcn_mfma_f32_16x16x32_bf16(a, b, c, 0, 0, 0);
}

__device__ __forceinline__ unsigned short f2bf(float f) {
    unsigned int u = __float_as_uint(f);
    unsigned int r = (u + 0x7fffu + ((u >> 16) & 1u)) >> 16;
    return (unsigned short)r;
}

__device__ __forceinline__ float wredsum(float v) {
#pragma unroll
    for (int o = 32; o > 0; o >>= 1) v += __shfl_xor(v, o);
    return v;
}
__device__ __forceinline__ float wredmax(float v) {
#pragma unroll
    for (int o = 32; o > 0; o >>= 1) v = fmaxf(v, __shfl_xor(v, o));
    return v;
}

// ---------------- weight absmean partials (deterministic two-pass) ----------
__global__ __launch_bounds__(256) void wabssum(const float* __restrict__ w0, const float* __restrict__ w1,
                                               const float* __restrict__ w2, const float* __restrict__ w3,
                                               float* __restrict__ part) {
    int widx = blockIdx.x >> 5, b = blockIdx.x & 31;
    const float* w = (widx == 0) ? w0 : (widx == 1) ? w1 : (widx == 2) ? w2 : w3;
    const float4* w4 = (const float4*)w;
    int tid = threadIdx.x;
    float s = 0.f;
    int base = b * 8192 + tid;  // float4 units; 32 blocks * 8192 = 262144 = 1M floats
#pragma unroll
    for (int i = 0; i < 32; ++i) {
        float4 v = w4[base + i * 256];
        s += fabsf(v.x) + fabsf(v.y) + fabsf(v.z) + fabsf(v.w);
    }
    s = wredsum(s);
    __shared__ float red[4];
    int wid = tid >> 6, lid = tid & 63;
    if (lid == 0) red[wid] = s;
    __syncthreads();
    if (tid == 0) part[blockIdx.x] = red[0] + red[1] + red[2] + red[3];
}

// ---------------- ternary weight quant -> bf16 {-1,0,1} ---------------------
__global__ __launch_bounds__(256) void wquant(const float* __restrict__ w0, const float* __restrict__ w1,
                                              const float* __restrict__ w2, const float* __restrict__ w3,
                                              const float* __restrict__ part, unsigned short* __restrict__ wbf) {
    int widx = blockIdx.x >> 6, b = blockIdx.x & 63;
    const float* w = (widx == 0) ? w0 : (widx == 1) ? w1 : (widx == 2) ? w2 : w3;
    float s = 0.f;
#pragma unroll
    for (int i = 0; i < 32; ++i) s += part[widx * 32 + i];
    s = fmaxf(s * (1.f / 1048576.f), 1e-5f);
    float inv = 1.f / s;
    const float4* w4 = (const float4*)w;
    unsigned short* dst = wbf + (size_t)widx * 1048576;
    int tid = threadIdx.x;
#pragma unroll
    for (int it = 0; it < 16; ++it) {
        int i4 = b * 4096 + it * 256 + tid;
        float4 v = w4[i4];
        float q0 = fminf(fmaxf(rintf(v.x * inv), -1.f), 1.f);
        float q1 = fminf(fmaxf(rintf(v.y * inv), -1.f), 1.f);
        float q2 = fminf(fmaxf(rintf(v.z * inv), -1.f), 1.f);
        float q3 = fminf(fmaxf(rintf(v.w * inv), -1.f), 1.f);
        ((ushort4*)dst)[i4] = make_ushort4(f2bf(q0), f2bf(q1), f2bf(q2), f2bf(q3));
    }
}

// ------------- fused rmsnorm + per-token absmax quant (NP planes) -----------
template <int NP>
__global__ __launch_bounds__(256) void actquant(const float* __restrict__ x, const float* __restrict__ g0,
                                                const float* __restrict__ g1, const float* __restrict__ g2,
                                                unsigned short* __restrict__ aq, float* __restrict__ ascale) {
    int m = blockIdx.x, tid = threadIdx.x;
    int wid = tid >> 6, lid = tid & 63;
    __shared__ float red[4];
    float4 xv = ((const float4*)(x + (size_t)m * 1024))[tid];
    float ss = xv.x * xv.x + xv.y * xv.y + xv.z * xv.z + xv.w * xv.w;
    ss = wredsum(ss);
    if (lid == 0) red[wid] = ss;
    __syncthreads();
    float rstd = rsqrtf((red[0] + red[1] + red[2] + red[3]) * (1.f / 1024.f) + 1e-6f);
    const float* gs[3] = {g0, g1, g2};
#pragma unroll
    for (int p = 0; p < NP; ++p) {
        float4 gv = ((const float4*)gs[p])[tid];
        float a0 = xv.x * gv.x * rstd, a1 = xv.y * gv.y * rstd;
        float a2 = xv.z * gv.z * rstd, a3 = xv.w * gv.w * rstd;
        float am = fmaxf(fmaxf(fabsf(a0), fabsf(a1)), fmaxf(fabsf(a2), fabsf(a3)));
        am = wredmax(am);
        __syncthreads();  // protect red from previous use
        if (lid == 0) red[wid] = am;
        __syncthreads();
        float rm = fmaxf(fmaxf(red[0], red[1]), fmaxf(red[2], red[3]));
        float scale = 127.f / fmaxf(rm, 1e-5f);
        float q0 = fminf(fmaxf(rintf(a0 * scale), -128.f), 127.f);
        float q1 = fminf(fmaxf(rintf(a1 * scale), -128.f), 127.f);
        float q2 = fminf(fmaxf(rintf(a2 * scale), -128.f), 127.f);
        float q3 = fminf(fmaxf(rintf(a3 * scale), -128.f), 127.f);
        ((ushort4*)(aq + (size_t)p * 4194304 + (size_t)m * 1024))[tid] =
            make_ushort4(f2bf(q0), f2bf(q1), f2bf(q2), f2bf(q3));
        if (tid == 0) ascale[p * 4096 + m] = scale;
    }
}

// ---------------- bf16 integer GEMM: [4096,1024] x [1024,1024]^T ------------
// MODE 0: out bf16 [B,H,T,D]; MODE 1: out bf16 [BH,D,T] (V transposed); MODE 2: out f32 [M,N]
template <int MODE>
__global__ __launch_bounds__(256) void gemm_bf16(const unsigned short* __restrict__ A,
                                                 const float* __restrict__ asc,
                                                 const unsigned short* __restrict__ W,
                                                 const float* __restrict__ part, void* __restrict__ outp) {
    __shared__ alignas(16) unsigned short As[64][72];  // pad 72 -> 2-way-max bank alias
    __shared__ alignas(16) unsigned short Bs[64][72];
    int bid = blockIdx.x;
    int bm = bid & 63, bn = bid >> 6;
    int tid = threadIdx.x;
    int w = tid >> 6, l = tid & 63;
    int wr = w >> 1, wc = w & 1;
    int lr = l & 15, lh = l >> 4;
    float s = 0.f;
#pragma unroll
    for (int i = 0; i < 32; ++i) s += part[i];
    float s_w = fmaxf(s * (1.f / 1048576.f), 1e-5f);

    f32x4 acc[2][2] = {};
    int strow = tid >> 3;          // 0..31
    int stcol = (tid & 7) * 8;     // short offset, 16B chunks
    const unsigned short* Abase = A + (size_t)(bm * 64) * 1024;
    const unsigned short* Wbase = W + (size_t)(bn * 64) * 1024;

    for (int kt = 0; kt < 16; ++kt) {
        int k0 = kt * 64;
        __syncthreads();
#pragma unroll
        for (int ps = 0; ps < 2; ++ps) {
            int row = ps * 32 + strow;
            *(int4*)&As[row][stcol] = *(const int4*)&Abase[(size_t)row * 1024 + k0 + stcol];
            *(int4*)&Bs[row][stcol] = *(const int4*)&Wbase[(size_t)row * 1024 + k0 + stcol];
        }
        __syncthreads();
#pragma unroll
        for (int ks = 0; ks < 2; ++ks) {
            int kb = ks * 32 + lh * 8;
            bf16x8 af[2], bfr[2];
            af[0] = *(const bf16x8*)&As[wr * 32 + lr][kb];
            af[1] = *(const bf16x8*)&As[wr * 32 + 16 + lr][kb];
            bfr[0] = *(const bf16x8*)&Bs[wc * 32 + lr][kb];
            bfr[1] = *(const bf16x8*)&Bs[wc * 32 + 16 + lr][kb];
#pragma unroll
            for (int mi = 0; mi < 2; ++mi)
#pragma unroll
                for (int ni = 0; ni < 2; ++ni) acc[mi][ni] = mfma16(af[mi], bfr[ni], acc[mi][ni]);
        }
    }
#pragma unroll
    for (int mi = 0; mi < 2; ++mi) {
        int mbase = bm * 64 + wr * 32 + mi * 16 + lh * 4;
#pragma unroll
        for (int ni = 0; ni < 2; ++ni) {
            int n = bn * 64 + wc * 32 + ni * 16 + lr;
            if (MODE == 1) {
                int b = mbase >> 11, t0 = mbase & 2047;
                int h = n >> 6, d = n & 63;
                ushort4 st;
                st.x = f2bf(acc[mi][ni][0] * s_w / asc[mbase + 0]);
                st.y = f2bf(acc[mi][ni][1] * s_w / asc[mbase + 1]);
                st.z = f2bf(acc[mi][ni][2] * s_w / asc[mbase + 2]);
                st.w = f2bf(acc[mi][ni][3] * s_w / asc[mbase + 3]);
                *(ushort4*)&((unsigned short*)outp)[(size_t)(b * 16 + h) * 131072 + (size_t)d * 2048 + t0] = st;
            } else {
#pragma unroll
                for (int i = 0; i < 4; ++i) {
                    int m = mbase + i;
                    float val = acc[mi][ni][i] * s_w / asc[m];
                    if (MODE == 0) {
                        int b = m >> 11, t = m & 2047, h = n >> 6, d = n & 63;
                        ((unsigned short*)outp)[(size_t)(b * 16 + h) * 131072 + (size_t)t * 64 + d] = f2bf(val);
                    } else {
                        ((float*)outp)[(size_t)m * 1024 + n] = val;
                    }
                }
            }
        }
    }
}

// ---------------- flash attention (causal, 16 heads, D=64) ------------------
__global__ __launch_bounds__(256) void attn(const unsigned short* __restrict__ qb,
                                            const unsigned short* __restrict__ kb,
                                            const unsigned short* __restrict__ vt, float* __restrict__ y) {
    int qblk = blockIdx.x, bh = blockIdx.y;
    int tid = threadIdx.x, w = tid >> 6, l = tid & 63;
    int lr = l & 15, lh = l >> 4;
    int q0 = qblk * 64 + w * 16;
    const unsigned short* qbase = qb + (size_t)bh * 131072;
    const unsigned short* kbase = kb + (size_t)bh * 131072;
    const unsigned short* vbase = vt + (size_t)bh * 131072;

    bf16x8 qf0 = *(const bf16x8*)&qbase[(size_t)(q0 + lr) * 64 + lh * 8];
    bf16x8 qf1 = *(const bf16x8*)&qbase[(size_t)(q0 + lr) * 64 + 32 + lh * 8];

    f32x4 o0 = {}, o1 = {}, o2 = {}, o3 = {};
    float ninf = -__builtin_inff();
    float mrow[4] = {ninf, ninf, ninf, ninf};
    float lrow[4] = {0.f, 0.f, 0.f, 0.f};
    __shared__ alignas(16) unsigned short plds[4][16][40];

    int ntiles = (q0 + 47) >> 5;
    for (int t = 0; t < ntiles; ++t) {
        int kv0 = t << 5;
        f32x4 s0 = {}, s1 = {};
        {
            bf16x8 kf;
            kf = *(const bf16x8*)&kbase[(size_t)(kv0 + lr) * 64 + lh * 8];
            s0 = mfma16(qf0, kf, s0);
            kf = *(const bf16x8*)&kbase[(size_t)(kv0 + lr) * 64 + 32 + lh * 8];
            s0 = mfma16(qf1, kf, s0);
            kf = *(const bf16x8*)&kbase[(size_t)(kv0 + 16 + lr) * 64 + lh * 8];
            s1 = mfma16(qf0, kf, s1);
            kf = *(const bf16x8*)&kbase[(size_t)(kv0 + 16 + lr) * 64 + 32 + lh * 8];
            s1 = mfma16(qf1, kf, s1);
        }
        float corr[4];
#pragma unroll
        for (int r = 0; r < 4; ++r) {
            int qrow = q0 + lh * 4 + r;
            float v0 = (kv0 + lr <= qrow) ? s0[r] * 0.125f : ninf;
            float v1 = (kv0 + 16 + lr <= qrow) ? s1[r] * 0.125f : ninf;
            float mt = fmaxf(v0, v1);
#pragma unroll
            for (int off = 8; off; off >>= 1) mt = fmaxf(mt, __shfl_xor(mt, off));
            float mn = fmaxf(mrow[r], mt);
            float c = __expf(mrow[r] - mn);
            float p0 = __expf(v0 - mn), p1 = __expf(v1 - mn);
            float rs = p0 + p1;
#pragma unroll
            for (int off = 8; off; off >>= 1) rs += __shfl_xor(rs, off);
            lrow[r] = lrow[r] * c + rs;
            mrow[r] = mn;
            corr[r] = c;
            plds[w][lh * 4 + r][lr] = f2bf(p0);
            plds[w][lh * 4 + r][lr + 16] = f2bf(p1);
        }
#pragma unroll
        for (int r = 0; r < 4; ++r) {
            o0[r] *= corr[r]; o1[r] *= corr[r]; o2[r] *= corr[r]; o3[r] *= corr[r];
        }
        bf16x8 pf = *(const bf16x8*)&plds[w][lr][lh * 8];
        bf16x8 vf;
        vf = *(const bf16x8*)&vbase[(size_t)(lr) * 2048 + kv0 + lh * 8];       o0 = mfma16(pf, vf, o0);
        vf = *(const bf16x8*)&vbase[(size_t)(16 + lr) * 2048 + kv0 + lh * 8];  o1 = mfma16(pf, vf, o1);
        vf = *(const bf16x8*)&vbase[(size_t)(32 + lr) * 2048 + kv0 + lh * 8];  o2 = mfma16(pf, vf, o2);
        vf = *(const bf16x8*)&vbase[(size_t)(48 + lr) * 2048 + kv0 + lh * 8];  o3 = mfma16(pf, vf, o3);
    }
    int b = bh >> 4, h = bh & 15;
#pragma unroll
    for (int r = 0; r < 4; ++r) {
        int qrow = q0 + lh * 4 + r;
        float invl = 1.f / lrow[r];
        float* yr = y + (size_t)(b * 2048 + qrow) * 1024 + h * 64;
        yr[lr] = o0[r] * invl;
        yr[16 + lr] = o1[r] * invl;
        yr[32 + lr] = o2[r] * invl;
        yr[48 + lr] = o3[r] * invl;
    }
}

extern "C" void kernel_launch(void* const* d_in, const int* in_sizes, int n_in,
                              void* d_out, int out_size, void* d_ws, size_t ws_size,
                              hipStream_t stream) {
    const float* x  = (const float*)d_in[0];
    const float* wq = (const float*)d_in[1];
    const float* wk = (const float*)d_in[2];
    const float* wv = (const float*)d_in[3];
    const float* wo = (const float*)d_in[4];
    const float* gq = (const float*)d_in[5];
    const float* gk = (const float*)d_in[6];
    const float* gv = (const float*)d_in[7];
    const float* go = (const float*)d_in[8];

    char* ws = (char*)d_ws;
    size_t off = 0;
    auto alloc = [&](size_t bytes) {
        size_t o = off;
        off += (bytes + 255) & ~(size_t)255;
        return o;
    };
    float* part = (float*)(ws + alloc(128 * 4));
    unsigned short* wbf = (unsigned short*)(ws + alloc(4ull * 1048576 * 2));   // 4 x [1024][1024] bf16
    unsigned short* abf = (unsigned short*)(ws + alloc(3ull * 4194304 * 2));   // 3 x [4096][1024] bf16
    float* asc = (float*)(ws + alloc(3ull * 4096 * 4));
    unsigned short* qbf = (unsigned short*)(ws + alloc(4194304ull * 2));       // [BH][T][D]
    unsigned short* kbf = (unsigned short*)(ws + alloc(4194304ull * 2));       // [BH][T][D]
    unsigned short* vtb = (unsigned short*)(ws + alloc(4194304ull * 2));       // [BH][D][T]
    float* ybuf = (float*)(ws + alloc(4194304ull * 4));                        // [B,T,C] f32
    unsigned short* ybf = (unsigned short*)(ws + alloc(4194304ull * 2));
    float* ysc = (float*)(ws + alloc(4096 * 4));
    (void)ws_size; (void)in_sizes; (void)n_in; (void)out_size;

    wabssum<<<128, 256, 0, stream>>>(wq, wk, wv, wo, part);
    wquant<<<256, 256, 0, stream>>>(wq, wk, wv, wo, part, wbf);
    actquant<3><<<4096, 256, 0, stream>>>(x, gq, gk, gv, abf, asc);
    gemm_bf16<0><<<1024, 256, 0, stream>>>(abf,               asc,        wbf,               part,      qbf);
    gemm_bf16<0><<<1024, 256, 0, stream>>>(abf + 4194304,     asc + 4096, wbf + 1048576,     part + 32, kbf);
    gemm_bf16<1><<<1024, 256, 0, stream>>>(abf + 2 * 4194304, asc + 8192, wbf + 2 * 1048576, part + 64, vtb);
    attn<<<dim3(32, 32), 256, 0, stream>>>(qbf, kbf, vtb, ybuf);
    actquant<1><<<4096, 256, 0, stream>>>(ybuf, go, go, go, ybf, ysc);
    gemm_bf16<2><<<1024, 256, 0, stream>>>(ybf, ysc, wbf + 3 * 1048576, part + 96, (float*)d_out);
}

// Round 2
// 264.592 us; speedup vs baseline: 1.3961x; 1.3961x over previous
//
#include <hip/hip_runtime.h>
#include <hip/hip_bf16.h>

// B=2, T=2048, C=1024, H=16, D=64, M=B*T=4096
// All GEMMs: exact integer math via bf16 MFMA (ints <= 2^24 exact in fp32 accum).

typedef __attribute__((ext_vector_type(8))) short bf16x8;
typedef __attribute__((ext_vector_type(4))) float f32x4;

__device__ __forceinline__ f32x4 mfma16(bf16x8 a, bf16x8 b, f32x4 c) {
    return __builtin_amdgcn_mfma_f32_16x16x32_bf16(a, b, c, 0, 0, 0);
}

__device__ __forceinline__ unsigned short f2bf(float f) {
    unsigned int u = __float_as_uint(f);
    unsigned int r = (u + 0x7fffu + ((u >> 16) & 1u)) >> 16;
    return (unsigned short)r;
}

__device__ __forceinline__ float wredsum(float v) {
#pragma unroll
    for (int o = 32; o > 0; o >>= 1) v += __shfl_xor(v, o);
    return v;
}
__device__ __forceinline__ float wredmax(float v) {
#pragma unroll
    for (int o = 32; o > 0; o >>= 1) v = fmaxf(v, __shfl_xor(v, o));
    return v;
}

// ---------------- weight absmean partials (deterministic two-pass) ----------
__global__ __launch_bounds__(256) void wabssum(const float* __restrict__ w0, const float* __restrict__ w1,
                                               const float* __restrict__ w2, const float* __restrict__ w3,
                                               float* __restrict__ part) {
    int widx = blockIdx.x >> 5, b = blockIdx.x & 31;
    const float* w = (widx == 0) ? w0 : (widx == 1) ? w1 : (widx == 2) ? w2 : w3;
    const float4* w4 = (const float4*)w;
    int tid = threadIdx.x;
    float s = 0.f;
    int base = b * 8192 + tid;  // float4 units; 32 blocks * 8192 = 262144 = 1M floats
#pragma unroll
    for (int i = 0; i < 32; ++i) {
        float4 v = w4[base + i * 256];
        s += fabsf(v.x) + fabsf(v.y) + fabsf(v.z) + fabsf(v.w);
    }
    s = wredsum(s);
    __shared__ float red[4];
    int wid = tid >> 6, lid = tid & 63;
    if (lid == 0) red[wid] = s;
    __syncthreads();
    if (tid == 0) part[blockIdx.x] = red[0] + red[1] + red[2] + red[3];
}

// ---------------- ternary weight quant -> bf16 {-1,0,1} ---------------------
__global__ __launch_bounds__(256) void wquant(const float* __restrict__ w0, const float* __restrict__ w1,
                                              const float* __restrict__ w2, const float* __restrict__ w3,
                                              const float* __restrict__ part, unsigned short* __restrict__ wbf) {
    int widx = blockIdx.x >> 6, b = blockIdx.x & 63;
    const float* w = (widx == 0) ? w0 : (widx == 1) ? w1 : (widx == 2) ? w2 : w3;
    float s = 0.f;
#pragma unroll
    for (int i = 0; i < 32; ++i) s += part[widx * 32 + i];
    s = fmaxf(s * (1.f / 1048576.f), 1e-5f);
    float inv = 1.f / s;
    const float4* w4 = (const float4*)w;
    unsigned short* dst = wbf + (size_t)widx * 1048576;
    int tid = threadIdx.x;
#pragma unroll
    for (int it = 0; it < 16; ++it) {
        int i4 = b * 4096 + it * 256 + tid;
        float4 v = w4[i4];
        float q0 = fminf(fmaxf(rintf(v.x * inv), -1.f), 1.f);
        float q1 = fminf(fmaxf(rintf(v.y * inv), -1.f), 1.f);
        float q2 = fminf(fmaxf(rintf(v.z * inv), -1.f), 1.f);
        float q3 = fminf(fmaxf(rintf(v.w * inv), -1.f), 1.f);
        ((ushort4*)dst)[i4] = make_ushort4(f2bf(q0), f2bf(q1), f2bf(q2), f2bf(q3));
    }
}

// ------------- fused rmsnorm + per-token absmax quant (NP planes) -----------
template <int NP>
__global__ __launch_bounds__(256) void actquant(const float* __restrict__ x, const float* __restrict__ g0,
                                                const float* __restrict__ g1, const float* __restrict__ g2,
                                                unsigned short* __restrict__ aq, float* __restrict__ ascale) {
    int m = blockIdx.x, tid = threadIdx.x;
    int wid = tid >> 6, lid = tid & 63;
    __shared__ float red[4];
    float4 xv = ((const float4*)(x + (size_t)m * 1024))[tid];
    float ss = xv.x * xv.x + xv.y * xv.y + xv.z * xv.z + xv.w * xv.w;
    ss = wredsum(ss);
    if (lid == 0) red[wid] = ss;
    __syncthreads();
    float rstd = rsqrtf((red[0] + red[1] + red[2] + red[3]) * (1.f / 1024.f) + 1e-6f);
    const float* gs[3] = {g0, g1, g2};
#pragma unroll
    for (int p = 0; p < NP; ++p) {
        float4 gv = ((const float4*)gs[p])[tid];
        float a0 = xv.x * gv.x * rstd, a1 = xv.y * gv.y * rstd;
        float a2 = xv.z * gv.z * rstd, a3 = xv.w * gv.w * rstd;
        float am = fmaxf(fmaxf(fabsf(a0), fabsf(a1)), fmaxf(fabsf(a2), fabsf(a3)));
        am = wredmax(am);
        __syncthreads();  // protect red from previous use
        if (lid == 0) red[wid] = am;
        __syncthreads();
        float rm = fmaxf(fmaxf(red[0], red[1]), fmaxf(red[2], red[3]));
        float scale = 127.f / fmaxf(rm, 1e-5f);
        float q0 = fminf(fmaxf(rintf(a0 * scale), -128.f), 127.f);
        float q1 = fminf(fmaxf(rintf(a1 * scale), -128.f), 127.f);
        float q2 = fminf(fmaxf(rintf(a2 * scale), -128.f), 127.f);
        float q3 = fminf(fmaxf(rintf(a3 * scale), -128.f), 127.f);
        ((ushort4*)(aq + (size_t)p * 4194304 + (size_t)m * 1024))[tid] =
            make_ushort4(f2bf(q0), f2bf(q1), f2bf(q2), f2bf(q3));
        if (tid == 0) ascale[p * 4096 + m] = scale;
    }
}

// ---------------- bf16 integer GEMM: [4096,1024] x [1024,1024]^T ------------
// MODE 0: out bf16 [B,H,T,D]; MODE 1: out bf16 [BH,D,T] (V transposed); MODE 2: out f32 [M,N]
template <int MODE>
__global__ __launch_bounds__(256) void gemm_bf16(const unsigned short* __restrict__ A,
                                                 const float* __restrict__ asc,
                                                 const unsigned short* __restrict__ W,
                                                 const float* __restrict__ part, void* __restrict__ outp) {
    __shared__ alignas(16) unsigned short As[64][72];  // pad 72 -> 2-way-max bank alias
    __shared__ alignas(16) unsigned short Bs[64][72];
    int bid = blockIdx.x;
    int bm = bid & 63, bn = bid >> 6;
    int tid = threadIdx.x;
    int w = tid >> 6, l = tid & 63;
    int wr = w >> 1, wc = w & 1;
    int lr = l & 15, lh = l >> 4;
    float s = 0.f;
#pragma unroll
    for (int i = 0; i < 32; ++i) s += part[i];
    float s_w = fmaxf(s * (1.f / 1048576.f), 1e-5f);

    f32x4 acc[2][2] = {};
    int strow = tid >> 3;          // 0..31
    int stcol = (tid & 7) * 8;     // short offset, 16B chunks
    const unsigned short* Abase = A + (size_t)(bm * 64) * 1024;
    const unsigned short* Wbase = W + (size_t)(bn * 64) * 1024;

    for (int kt = 0; kt < 16; ++kt) {
        int k0 = kt * 64;
        __syncthreads();
#pragma unroll
        for (int ps = 0; ps < 2; ++ps) {
            int row = ps * 32 + strow;
            *(int4*)&As[row][stcol] = *(const int4*)&Abase[(size_t)row * 1024 + k0 + stcol];
            *(int4*)&Bs[row][stcol] = *(const int4*)&Wbase[(size_t)row * 1024 + k0 + stcol];
        }
        __syncthreads();
#pragma unroll
        for (int ks = 0; ks < 2; ++ks) {
            int kb = ks * 32 + lh * 8;
            bf16x8 af[2], bfr[2];
            af[0] = *(const bf16x8*)&As[wr * 32 + lr][kb];
            af[1] = *(const bf16x8*)&As[wr * 32 + 16 + lr][kb];
            bfr[0] = *(const bf16x8*)&Bs[wc * 32 + lr][kb];
            bfr[1] = *(const bf16x8*)&Bs[wc * 32 + 16 + lr][kb];
#pragma unroll
            for (int mi = 0; mi < 2; ++mi)
#pragma unroll
                for (int ni = 0; ni < 2; ++ni) acc[mi][ni] = mfma16(af[mi], bfr[ni], acc[mi][ni]);
        }
    }
#pragma unroll
    for (int mi = 0; mi < 2; ++mi) {
        int mbase = bm * 64 + wr * 32 + mi * 16 + lh * 4;
#pragma unroll
        for (int ni = 0; ni < 2; ++ni) {
            int n = bn * 64 + wc * 32 + ni * 16 + lr;
            if (MODE == 1) {
                int b = mbase >> 11, t0 = mbase & 2047;
                int h = n >> 6, d = n & 63;
                ushort4 st;
                st.x = f2bf(acc[mi][ni][0] * s_w / asc[mbase + 0]);
                st.y = f2bf(acc[mi][ni][1] * s_w / asc[mbase + 1]);
                st.z = f2bf(acc[mi][ni][2] * s_w / asc[mbase + 2]);
                st.w = f2bf(acc[mi][ni][3] * s_w / asc[mbase + 3]);
                *(ushort4*)&((unsigned short*)outp)[(size_t)(b * 16 + h) * 131072 + (size_t)d * 2048 + t0] = st;
            } else {
#pragma unroll
                for (int i = 0; i < 4; ++i) {
                    int m = mbase + i;
                    float val = acc[mi][ni][i] * s_w / asc[m];
                    if (MODE == 0) {
                        int b = m >> 11, t = m & 2047, h = n >> 6, d = n & 63;
                        ((unsigned short*)outp)[(size_t)(b * 16 + h) * 131072 + (size_t)t * 64 + d] = f2bf(val);
                    } else {
                        ((float*)outp)[(size_t)m * 1024 + n] = val;
                    }
                }
            }
        }
    }
}

// ---------------- flash attention (causal, 16 heads, D=64) ------------------
// 1 wave per block; each wave owns one 16-row q-chunk; heavy chunks dispatched
// first for dynamic load balance; K/V register double-buffer prefetch.
__global__ __launch_bounds__(64) void attn(const unsigned short* __restrict__ qb,
                                           const unsigned short* __restrict__ kb,
                                           const unsigned short* __restrict__ vt, float* __restrict__ y) {
    int blk = blockIdx.x;
    int bh = blk & 31;
    int c = 127 - (blk >> 5);  // chunk 0..127, heaviest first
    int q0 = c << 4;
    int l = threadIdx.x & 63;
    int lr = l & 15, lh = l >> 4;
    const unsigned short* qbase = qb + (size_t)bh * 131072;
    const unsigned short* kbase = kb + (size_t)bh * 131072;
    const unsigned short* vbase = vt + (size_t)bh * 131072;

    bf16x8 qf0 = *(const bf16x8*)&qbase[(size_t)(q0 + lr) * 64 + lh * 8];
    bf16x8 qf1 = *(const bf16x8*)&qbase[(size_t)(q0 + lr) * 64 + 32 + lh * 8];

    f32x4 o0 = {}, o1 = {}, o2 = {}, o3 = {};
    float ninf = -__builtin_inff();
    float mrow[4] = {ninf, ninf, ninf, ninf};
    float lrow[4] = {0.f, 0.f, 0.f, 0.f};
    __shared__ alignas(16) unsigned short plds[16][40];

    int ntiles = (q0 + 47) >> 5;

    auto LOADK = [&](int kv0, bf16x8* k) {
        k[0] = *(const bf16x8*)&kbase[(size_t)(kv0 + lr) * 64 + lh * 8];
        k[1] = *(const bf16x8*)&kbase[(size_t)(kv0 + lr) * 64 + 32 + lh * 8];
        k[2] = *(const bf16x8*)&kbase[(size_t)(kv0 + 16 + lr) * 64 + lh * 8];
        k[3] = *(const bf16x8*)&kbase[(size_t)(kv0 + 16 + lr) * 64 + 32 + lh * 8];
    };
    auto LOADV = [&](int kv0, bf16x8* v) {
        v[0] = *(const bf16x8*)&vbase[(size_t)(lr)*2048 + kv0 + lh * 8];
        v[1] = *(const bf16x8*)&vbase[(size_t)(16 + lr) * 2048 + kv0 + lh * 8];
        v[2] = *(const bf16x8*)&vbase[(size_t)(32 + lr) * 2048 + kv0 + lh * 8];
        v[3] = *(const bf16x8*)&vbase[(size_t)(48 + lr) * 2048 + kv0 + lh * 8];
    };
    auto PROCESS = [&](int t, bf16x8* k, bf16x8* v) {
        int kv0 = t << 5;
        f32x4 s0 = {}, s1 = {};
        s0 = mfma16(qf0, k[0], s0);
        s0 = mfma16(qf1, k[1], s0);
        s1 = mfma16(qf0, k[2], s1);
        s1 = mfma16(qf1, k[3], s1);
        float corr[4];
#pragma unroll
        for (int r = 0; r < 4; ++r) {
            int qrow = q0 + lh * 4 + r;
            float v0 = (kv0 + lr <= qrow) ? s0[r] * 0.125f : ninf;
            float v1 = (kv0 + 16 + lr <= qrow) ? s1[r] * 0.125f : ninf;
            float mt = fmaxf(v0, v1);
#pragma unroll
            for (int off = 8; off; off >>= 1) mt = fmaxf(mt, __shfl_xor(mt, off));
            float mn = fmaxf(mrow[r], mt);
            float cc = __expf(mrow[r] - mn);
            float p0 = __expf(v0 - mn), p1 = __expf(v1 - mn);
            float rs = p0 + p1;
#pragma unroll
            for (int off = 8; off; off >>= 1) rs += __shfl_xor(rs, off);
            lrow[r] = lrow[r] * cc + rs;
            mrow[r] = mn;
            corr[r] = cc;
            plds[lh * 4 + r][lr] = f2bf(p0);
            plds[lh * 4 + r][lr + 16] = f2bf(p1);
        }
#pragma unroll
        for (int r = 0; r < 4; ++r) {
            o0[r] *= corr[r];
            o1[r] *= corr[r];
            o2[r] *= corr[r];
            o3[r] *= corr[r];
        }
        bf16x8 pf = *(const bf16x8*)&plds[lr][lh * 8];
        o0 = mfma16(pf, v[0], o0);
        o1 = mfma16(pf, v[1], o1);
        o2 = mfma16(pf, v[2], o2);
        o3 = mfma16(pf, v[3], o3);
    };

    bf16x8 kA[4], vA[4], kB[4], vB[4];
    LOADK(0, kA);
    LOADV(0, vA);
    int t = 0;
    while (true) {
        if (t + 1 < ntiles) { LOADK((t + 1) << 5, kB); LOADV((t + 1) << 5, vB); }
        PROCESS(t, kA, vA);
        if (++t >= ntiles) break;
        if (t + 1 < ntiles) { LOADK((t + 1) << 5, kA); LOADV((t + 1) << 5, vA); }
        PROCESS(t, kB, vB);
        if (++t >= ntiles) break;
    }

    int b = bh >> 4, h = bh & 15;
#pragma unroll
    for (int r = 0; r < 4; ++r) {
        int qrow = q0 + lh * 4 + r;
        float invl = 1.f / lrow[r];
        float* yr = y + (size_t)(b * 2048 + qrow) * 1024 + h * 64;
        yr[lr] = o0[r] * invl;
        yr[16 + lr] = o1[r] * invl;
        yr[32 + lr] = o2[r] * invl;
        yr[48 + lr] = o3[r] * invl;
    }
}

extern "C" void kernel_launch(void* const* d_in, const int* in_sizes, int n_in,
                              void* d_out, int out_size, void* d_ws, size_t ws_size,
                              hipStream_t stream) {
    const float* x  = (const float*)d_in[0];
    const float* wq = (const float*)d_in[1];
    const float* wk = (const float*)d_in[2];
    const float* wv = (const float*)d_in[3];
    const float* wo = (const float*)d_in[4];
    const float* gq = (const float*)d_in[5];
    const float* gk = (const float*)d_in[6];
    const float* gv = (const float*)d_in[7];
    const float* go = (const float*)d_in[8];

    char* ws = (char*)d_ws;
    size_t off = 0;
    auto alloc = [&](size_t bytes) {
        size_t o = off;
        off += (bytes + 255) & ~(size_t)255;
        return o;
    };
    float* part = (float*)(ws + alloc(128 * 4));
    unsigned short* wbf = (unsigned short*)(ws + alloc(4ull * 1048576 * 2));   // 4 x [1024][1024] bf16
    unsigned short* abf = (unsigned short*)(ws + alloc(3ull * 4194304 * 2));   // 3 x [4096][1024] bf16
    float* asc = (float*)(ws + alloc(3ull * 4096 * 4));
    unsigned short* qbf = (unsigned short*)(ws + alloc(4194304ull * 2));       // [BH][T][D]
    unsigned short* kbf = (unsigned short*)(ws + alloc(4194304ull * 2));       // [BH][T][D]
    unsigned short* vtb = (unsigned short*)(ws + alloc(4194304ull * 2));       // [BH][D][T]
    float* ybuf = (float*)(ws + alloc(4194304ull * 4));                        // [B,T,C] f32
    unsigned short* ybf = (unsigned short*)(ws + alloc(4194304ull * 2));
    float* ysc = (float*)(ws + alloc(4096 * 4));
    (void)ws_size; (void)in_sizes; (void)n_in; (void)out_size;

    wabssum<<<128, 256, 0, stream>>>(wq, wk, wv, wo, part);
    wquant<<<256, 256, 0, stream>>>(wq, wk, wv, wo, part, wbf);
    actquant<3><<<4096, 256, 0, stream>>>(x, gq, gk, gv, abf, asc);
    gemm_bf16<0><<<1024, 256, 0, stream>>>(abf,               asc,        wbf,               part,      qbf);
    gemm_bf16<0><<<1024, 256, 0, stream>>>(abf + 4194304,     asc + 4096, wbf + 1048576,     part + 32, kbf);
    gemm_bf16<1><<<1024, 256, 0, stream>>>(abf + 2 * 4194304, asc + 8192, wbf + 2 * 1048576, part + 64, vtb);
    attn<<<4096, 64, 0, stream>>>(qbf, kbf, vtb, ybuf);
    actquant<1><<<4096, 256, 0, stream>>>(ybuf, go, go, go, ybf, ysc);
    gemm_bf16<2><<<1024, 256, 0, stream>>>(ybf, ysc, wbf + 3 * 1048576, part + 96, (float*)d_out);
}